// Round 8
// baseline (1578.343 us; speedup 1.0000x reference)
//
#include <hip/hip_runtime.h>

typedef short bf16x8 __attribute__((ext_vector_type(8)));
typedef float f32x4  __attribute__((ext_vector_type(4)));
typedef unsigned short u16;

static __device__ __forceinline__ u16 f2bf(float f) {
    unsigned int u = __builtin_bit_cast(unsigned int, f);
    u += 0x7FFFu + ((u >> 16) & 1u);   // round-to-nearest-even
    return (u16)(u >> 16);
}

static __device__ __forceinline__ void gload_lds16(const void* g, void* l) {
    __builtin_amdgcn_global_load_lds((const __attribute__((address_space(1))) void*)g,
                                     (__attribute__((address_space(3))) void*)l, 16, 0, 0);
}

// ---------------- Kernel 1: demodulate + convert weights to bf16 -------------
// wn[((tap*4 + cc)*128 + co)*32 + ci_in_chunk]  == kstep-major [k108][co128][ci32]
__global__ __launch_bounds__(256) void prep_w_k(const float* __restrict__ w,
                                                u16* __restrict__ wn) {
    const int co = blockIdx.x;
    const int t  = threadIdx.x;
    const float* wc = w + co * 3456;
    float s = 0.f;
    for (int i = t; i < 3456; i += 256) { float v = wc[i]; s += v * v; }
#pragma unroll
    for (int off = 32; off; off >>= 1) s += __shfl_down(s, off);
    __shared__ float red[4];
    __shared__ float dsh;
    if ((t & 63) == 0) red[t >> 6] = s;
    __syncthreads();
    if (t == 0) dsh = rsqrtf(red[0] + red[1] + red[2] + red[3] + 1e-8f);
    __syncthreads();
    const float d = dsh;
    for (int i = t; i < 3456; i += 256) {
        int ci = i / 27, tap = i - ci * 27;
        float v = wc[i] * d;
        wn[((tap * 4 + (ci >> 5)) * 128 + co) * 32 + (ci & 31)] = f2bf(v);
    }
}

// ---------------- Kernel 2: transpose x -> channels-grouped bf16 -------------
// xt[((b*16 + g)*32768 + d*1024 + h*32 + w)*8 + j] = bf16(x[b][g*8+j][d][h][w])
__global__ __launch_bounds__(256) void xpose_k(const float* __restrict__ x,
                                               u16* __restrict__ xt) {
    const int bid = blockIdx.x;
    const int b = bid >> 10, d = (bid >> 5) & 31, h = bid & 31;
    const int t = threadIdx.x;
    const int w = t & 31, cg = t >> 5;
    const int base_dhw = d * 1024 + h * 32 + w;
#pragma unroll
    for (int r = 0; r < 2; ++r) {
        int g = cg + r * 8;
        const float* src = x + ((size_t)(b * 128 + g * 8) << 15) + base_dhw;
        bf16x8 pk;
#pragma unroll
        for (int j = 0; j < 8; ++j) pk[j] = (short)f2bf(src[(size_t)j << 15]);
        *(bf16x8*)&xt[((size_t)((b * 16 + g) << 15) + base_dhw) * 8] = pk;
    }
}

// ---------------- Kernel 3: conv3d, reg-dbuf frags + 3-lead ring -------------
// 512 thr = 8 waves (4 M-slices x 2 co-halves). Tile M=256 (d2,h4,w32), N=128.
// Wave tile 64x64: acc 16 f32x4 = 64; frag dbuf +32 VGPR; 4 waves/SIMD,
// 2 blocks/CU (LDS 72 KB). Step k: ds_read frags(k+1) [buf (k+1)%3] ->
// stage st(k+3) [buf k%3] -> MFMA frags(k) (regs, zero LDS latency) ->
// lgkmcnt(0), vmcnt(3), s_barrier. Stage lead = 2 full steps.
#define KSX 1048576   // shorts: x advance per k-step (4 groups * 32768 * 8)
#define KSW 4096      // shorts: wn advance per k-step
#define RB  12288     // shorts: ring stride (8192 x + 4096 w)
__global__ __launch_bounds__(512, 4) void conv_mx(
    const u16* __restrict__ wsb, const float* __restrict__ bias,
    float* __restrict__ out) {
    __shared__ __align__(16) u16 lds[3 * RB];     // 73728 B
    const u16* xt = wsb + 524288;
    const u16* wn = wsb + 512;
    const u16* zp = wsb;                          // zero page (memset)

    const int t = threadIdx.x, lane = t & 63, wid = t >> 6;
    const int ll = lane & 15, g = lane >> 4;
    const int mslice = wid >> 1, ncol = wid & 1;

    int wg = ((blockIdx.x & 7) << 7) | (blockIdx.x >> 3);   // XCD swizzle
    const int b = wg >> 7, dt = (wg >> 3) & 15, ht = wg & 7;
    const int d0 = dt * 2, h0 = ht * 4;

    // loop-invariant ds_read offsets (shorts, within ring buffer)
    const int pos0 = mslice * 64 + ll;
    const int xro = pos0 * 32 + ((g ^ ((pos0 >> 1) & 3)) * 8);
    const int co0 = ncol * 64 + ll;
    const int wro = 8192 + co0 * 32 + ((g ^ ((co0 >> 1) & 3)) * 8);

    // staging lane constants (3 gload_lds per thread per k-step)
    const int posA = wid * 32 + (lane >> 2);
    const int slot = lane & 3;
    const int pdA = posA >> 7, phA = (posA >> 5) & 3, wA = posA & 31;
    const int gA = slot ^ ((posA >> 1) & 3);
    const int wco = wid * 16 + (lane >> 2);
    const u16* wsrc = wn + wco * 32 + ((slot ^ ((wco >> 1) & 3)) * 8);

    f32x4 acc[4][4];
#pragma unroll
    for (int i = 0; i < 4; ++i)
#pragma unroll
        for (int j = 0; j < 4; ++j) acc[i][j] = (f32x4){0.f, 0.f, 0.f, 0.f};

    // staging cursor
    int od_s = 0, oh_s = 0, ow_s = 0, cc_s = 0;
    const u16* xsA = xt; bool okA = false, okB = false;

    bf16x8 xa[4], wa[4], xb[4], wb[4];   // frag double-buffer

#define DO_STAGE(SB) { \
    if (cc_s == 0) { \
        int Dx = d0 + pdA - 1 + od_s, Hx = h0 + phA - 1 + oh_s, Wx = wA - 1 + ow_s; \
        bool dh_ = ((unsigned)Dx < 32u) && ((unsigned)Hx < 32u); \
        okA = dh_ && ((unsigned)Wx < 32u); \
        okB = dh_ && (Wx < 16); \
        xsA = xt + (long)((b * 16 + gA) * 32768 + Dx * 1024 + Hx * 32 + Wx) * 8; } \
    gload_lds16(okA ? (const void*)xsA : (const void*)zp, (void*)&lds[(SB)*RB + wid*1024]); \
    gload_lds16(okB ? (const void*)(xsA + 128) : (const void*)zp, (void*)&lds[(SB)*RB + wid*1024 + 512]); \
    gload_lds16((const void*)wsrc, (void*)&lds[(SB)*RB + 8192 + wid*512]); \
    xsA += KSX; wsrc += KSW; \
    if (++cc_s == 4) { cc_s = 0; \
        if (++ow_s == 3) { ow_s = 0; if (++oh_s == 3) { oh_s = 0; ++od_s; } } } }

#define RDFRAG(RD, XF, WF) { \
    _Pragma("unroll") for (int mf = 0; mf < 4; ++mf) \
        XF[mf] = *(const bf16x8*)&lds[(RD)*RB + xro + mf * 512]; \
    _Pragma("unroll") for (int nf = 0; nf < 4; ++nf) \
        WF[nf] = *(const bf16x8*)&lds[(RD)*RB + wro + nf * 512]; }

#define MFMACL(XF, WF) { \
    __builtin_amdgcn_s_setprio(1); \
    _Pragma("unroll") for (int mf = 0; mf < 4; ++mf) \
    _Pragma("unroll") for (int nf = 0; nf < 4; ++nf) \
        acc[mf][nf] = __builtin_amdgcn_mfma_f32_16x16x32_bf16(WF[nf], XF[mf], acc[mf][nf], 0, 0, 0); \
    __builtin_amdgcn_s_setprio(0); }

#define KSTEP(RD, SB, CX, CW, NX, NW, DOST, VMSTR) { \
    RDFRAG(RD, NX, NW); \
    if (DOST) DO_STAGE(SB); \
    MFMACL(CX, CW); \
    asm volatile("s_waitcnt lgkmcnt(0)" ::: "memory"); \
    asm volatile("s_waitcnt " VMSTR ::: "memory"); \
    asm volatile("s_barrier" ::: "memory"); }

    // prologue: stage k=0,1,2 into buf0,1,2
    DO_STAGE(0); DO_STAGE(1); DO_STAGE(2);          // 9 loads in flight
    asm volatile("s_waitcnt vmcnt(6)" ::: "memory"); // st(0) landed (mine)
    asm volatile("s_barrier" ::: "memory");          // st(0) landed (all)
    RDFRAG(0, xa, wa);                               // frags(0) -> A
    asm volatile("s_waitcnt lgkmcnt(0)" ::: "memory");
    asm volatile("s_waitcnt vmcnt(3)" ::: "memory"); // st(1) landed (mine)
    asm volatile("s_barrier" ::: "memory");          // frags(0) captured + st(1) all

    for (int m = 0; m < 17; ++m) {      // k = 0..101
        KSTEP(1, 0, xa, wa, xb, wb, 1, "vmcnt(3)");
        KSTEP(2, 1, xb, wb, xa, wa, 1, "vmcnt(3)");
        KSTEP(0, 2, xa, wa, xb, wb, 1, "vmcnt(3)");
        KSTEP(1, 0, xb, wb, xa, wa, 1, "vmcnt(3)");
        KSTEP(2, 1, xa, wa, xb, wb, 1, "vmcnt(3)");
        KSTEP(0, 2, xb, wb, xa, wa, 1, "vmcnt(3)");
    }
    KSTEP(1, 0, xa, wa, xb, wb, 1, "vmcnt(3)");     // k=102, st(105)
    KSTEP(2, 1, xb, wb, xa, wa, 1, "vmcnt(3)");     // k=103, st(106)
    KSTEP(0, 2, xa, wa, xb, wb, 1, "vmcnt(3)");     // k=104, st(107)
    KSTEP(1, 0, xb, wb, xa, wa, 0, "vmcnt(0)");     // k=105
    KSTEP(2, 0, xa, wa, xb, wb, 0, "vmcnt(0)");     // k=106
    MFMACL(xb, wb);                                  // k=107

    // epilogue: bias + leaky_relu + sqrt(2) + clamp, direct stores
    const int pd = mslice >> 1, phb = (mslice & 1) * 2;
#pragma unroll
    for (int nf = 0; nf < 4; ++nf) {
        f32x4 bb = *(const f32x4*)&bias[ncol * 64 + nf * 16 + g * 4];
#pragma unroll
        for (int mf = 0; mf < 4; ++mf) {
            const int wq = (mf & 1) * 16 + ll;
            const int hh = h0 + phb + (mf >> 1);
            float* orow = out + ((size_t)(b * 128 + ncol * 64 + nf * 16 + g * 4) << 15)
                          + (d0 + pd) * 1024 + hh * 32 + wq;
#pragma unroll
            for (int q = 0; q < 4; ++q) {
                float v = acc[mf][nf][q] + bb[q];
                v = v > 0.f ? v : v * 0.2f;
                v *= 1.41421356237f;
                v = fminf(fmaxf(v, -256.f), 256.f);
                orow[(size_t)q << 15] = v;
            }
        }
    }
#undef DO_STAGE
#undef RDFRAG
#undef MFMACL
#undef KSTEP
}

// ---------------- Fallback conv (R4, proven) if ws too small -----------------
#define NPOS 544
__global__ __launch_bounds__(256, 4) void conv_fb(
    const float* __restrict__ x, const u16* __restrict__ wn,
    const float* __restrict__ bias, float* __restrict__ out) {
    __shared__ __align__(16) u16 lds[NPOS * 32];
    float* ldsf = reinterpret_cast<float*>(lds);
    const int t = threadIdx.x;
    const int lane = t & 63;
    const int wid  = t >> 6;
    const int wr   = wid >> 1;
    const int wcn  = wid & 1;
    const int ll   = lane & 15;
    const int g    = lane >> 4;
    const int bid = blockIdx.x;
    const int b  = bid >> 8;
    const int dt = (bid >> 4) & 15, ht = bid & 15;
    const int d0 = dt * 2, h0 = ht * 2;
    const int sw  = t & 31;
    const int sg  = (t >> 5) & 3;
    const int rhi = t >> 7;
    f32x4 acc[4][4];
#pragma unroll
    for (int i = 0; i < 4; ++i)
#pragma unroll
        for (int j = 0; j < 4; ++j) acc[i][j] = (f32x4){0.f, 0.f, 0.f, 0.f};
    float bv[4][4];
#pragma unroll
    for (int nf = 0; nf < 4; ++nf) {
        f32x4 bb = *(const f32x4*)&bias[wcn * 64 + nf * 16 + g * 4];
#pragma unroll
        for (int q = 0; q < 4; ++q) bv[nf][q] = bb[q];
    }
    if (t < 128) {
        int pi  = t >> 2;
        int row = pi >> 1;
        int pos = row * 34 + (pi & 1) * 33;
        bf16x8 z = {0, 0, 0, 0, 0, 0, 0, 0};
        *(bf16x8*)&lds[pos * 32 + (t & 3) * 8] = z;
    }
    for (int c = 0; c < 4; ++c) {
        if (c) __syncthreads();
#pragma unroll
        for (int p = 0; p < 8; ++p) {
            int rowid = p * 2 + rhi;
            int pd = rowid >> 2, ph = rowid & 3;
            int d = d0 - 1 + pd, h = h0 - 1 + ph;
            bool ok = ((unsigned)d < 32u) && ((unsigned)h < 32u);
            const float* src = x + (((b * 128 + c * 32 + sg * 8) * 32 + d) * 32 + h) * 32 + sw;
            float v[8];
#pragma unroll
            for (int j = 0; j < 8; ++j) v[j] = ok ? src[j * 32768] : 0.f;
            bf16x8 pk;
#pragma unroll
            for (int j = 0; j < 8; ++j) pk[j] = (short)f2bf(v[j]);
            int pos = rowid * 34 + sw + 1;
            int sl = sg ^ ((pos >> 1) & 3);
            *(bf16x8*)&lds[pos * 32 + sl * 8] = pk;
        }
        __syncthreads();
        const u16* wbase = wn + c * 4096 + ((wcn * 64 + ll) * 32 + g * 8);
        bf16x8 wf[4];
#pragma unroll
        for (int nf = 0; nf < 4; ++nf) wf[nf] = *(const bf16x8*)&wbase[nf * 512];
#pragma unroll
        for (int tap = 0; tap < 27; ++tap) {
            const int od = tap / 9, oh = (tap / 3) % 3, ow = tap % 3;
            bf16x8 wfn[4];
            if (tap < 26) {
#pragma unroll
                for (int nf = 0; nf < 4; ++nf)
                    wfn[nf] = *(const bf16x8*)&wbase[(tap + 1) * 16384 + nf * 512];
            }
            bf16x8 xf[4];
#pragma unroll
            for (int mf = 0; mf < 4; ++mf) {
                int pos = ((wr + od) * 4 + (mf >> 1) + oh) * 34 + (mf & 1) * 16 + ll + ow;
                int sl = g ^ ((pos >> 1) & 3);
                xf[mf] = *(const bf16x8*)&lds[pos * 32 + sl * 8];
            }
            __builtin_amdgcn_s_setprio(1);
#pragma unroll
            for (int mf = 0; mf < 4; ++mf)
#pragma unroll
                for (int nf = 0; nf < 4; ++nf)
                    acc[mf][nf] = __builtin_amdgcn_mfma_f32_16x16x32_bf16(
                        wf[nf], xf[mf], acc[mf][nf], 0, 0, 0);
            __builtin_amdgcn_s_setprio(0);
            if (tap < 26) {
#pragma unroll
                for (int nf = 0; nf < 4; ++nf) wf[nf] = wfn[nf];
            }
        }
    }
#pragma unroll
    for (int p = 0; p < 4; ++p) {
        const int dd = p >> 1, hh = p & 1;
        __syncthreads();
        if (wr == dd) {
#pragma unroll
            for (int whalf = 0; whalf < 2; ++whalf) {
                const int mf = hh * 2 + whalf;
#pragma unroll
                for (int nf = 0; nf < 4; ++nf) {
#pragma unroll
                    for (int q = 0; q < 4; ++q) {
                        const int co = wcn * 64 + nf * 16 + g * 4 + q;
                        float v = acc[mf][nf][q] + bv[nf][q];
                        v = v > 0.f ? v : v * 0.2f;
                        v *= 1.41421356237f;
                        v = fminf(fmaxf(v, -256.f), 256.f);
                        ldsf[co * 33 + whalf * 16 + ll] = v;
                    }
                }
            }
        }
        __syncthreads();
#pragma unroll
        for (int it = 0; it < 4; ++it) {
            const int row = it * 32 + (t >> 3);
            const int ls  = t & 7;
            f32x4 v = *(f32x4*)&ldsf[row * 33 + ls * 4];
            *(f32x4*)&out[(size_t)(b * 128 + row) * 32768 +
                          (d0 + dd) * 1024 + (h0 + hh) * 32 + ls * 4] = v;
        }
    }
}

extern "C" void kernel_launch(void* const* d_in, const int* in_sizes, int n_in,
                              void* d_out, int out_size, void* d_ws, size_t ws_size,
                              hipStream_t stream) {
    const float* x    = (const float*)d_in[0];
    const float* w    = (const float*)d_in[1];
    const float* bias = (const float*)d_in[2];
    float* out        = (float*)d_out;
    u16* wsb          = (u16*)d_ws;

    hipMemsetAsync(d_ws, 0, 1024, stream);                 // zero page
    prep_w_k<<<128, 256, 0, stream>>>(w, wsb + 512);       // wn at +1KB

    if (ws_size >= 68157440ull) {
        xpose_k<<<8192, 256, 0, stream>>>(x, wsb + 524288);  // xt at +1MB
        conv_mx<<<1024, 512, 0, stream>>>(wsb, bias, out);
    } else {
        conv_fb<<<2048, 256, 0, stream>>>(x, wsb + 512, bias, out);
    }
}

// Round 9
// 696.036 us; speedup vs baseline: 2.2676x; 2.2676x over previous
//
#include <hip/hip_runtime.h>

typedef short bf16x8 __attribute__((ext_vector_type(8)));
typedef float f32x4  __attribute__((ext_vector_type(4)));
typedef unsigned short u16;

static __device__ __forceinline__ u16 f2bf(float f) {
    unsigned int u = __builtin_bit_cast(unsigned int, f);
    u += 0x7FFFu + ((u >> 16) & 1u);   // round-to-nearest-even
    return (u16)(u >> 16);
}

static __device__ __forceinline__ void gload_lds16(const void* g, void* l) {
    __builtin_amdgcn_global_load_lds((const __attribute__((address_space(1))) void*)g,
                                     (__attribute__((address_space(3))) void*)l, 16, 0, 0);
}

// ---------------- Kernel 1: demodulate + convert weights to bf16 -------------
// wn[((tap*4 + cc)*128 + co)*32 + ci_in_chunk]  == kstep-major [k108][co128][ci32]
__global__ __launch_bounds__(256) void prep_w_k(const float* __restrict__ w,
                                                u16* __restrict__ wn) {
    const int co = blockIdx.x;
    const int t  = threadIdx.x;
    const float* wc = w + co * 3456;
    float s = 0.f;
    for (int i = t; i < 3456; i += 256) { float v = wc[i]; s += v * v; }
#pragma unroll
    for (int off = 32; off; off >>= 1) s += __shfl_down(s, off);
    __shared__ float red[4];
    __shared__ float dsh;
    if ((t & 63) == 0) red[t >> 6] = s;
    __syncthreads();
    if (t == 0) dsh = rsqrtf(red[0] + red[1] + red[2] + red[3] + 1e-8f);
    __syncthreads();
    const float d = dsh;
    for (int i = t; i < 3456; i += 256) {
        int ci = i / 27, tap = i - ci * 27;
        float v = wc[i] * d;
        wn[((tap * 4 + (ci >> 5)) * 128 + co) * 32 + (ci & 31)] = f2bf(v);
    }
}

// ---------------- Kernel 2: transpose x -> channels-grouped bf16 -------------
// xt[((b*16 + g)*32768 + d*1024 + h*32 + w)*8 + j] = bf16(x[b][g*8+j][d][h][w])
__global__ __launch_bounds__(256) void xpose_k(const float* __restrict__ x,
                                               u16* __restrict__ xt) {
    const int bid = blockIdx.x;
    const int b = bid >> 10, d = (bid >> 5) & 31, h = bid & 31;
    const int t = threadIdx.x;
    const int w = t & 31, cg = t >> 5;
    const int base_dhw = d * 1024 + h * 32 + w;
#pragma unroll
    for (int r = 0; r < 2; ++r) {
        int g = cg + r * 8;
        const float* src = x + ((size_t)(b * 128 + g * 8) << 15) + base_dhw;
        bf16x8 pk;
#pragma unroll
        for (int j = 0; j < 8; ++j) pk[j] = (short)f2bf(src[(size_t)j << 15]);
        *(bf16x8*)&xt[((size_t)((b * 16 + g) << 15) + base_dhw) * 8] = pk;
    }
}

// ---------------- Kernel 3: conv3d — w global->reg, x ring-3 in LDS ----------
// 512 thr = 8 waves (4 M-slices x 2 co-halves). Tile M=256 (d2,h4,w32), N=128.
// Wave tile 64x64: acc 64 VGPR + wf/wfn dbuf 32 VGPR. 4 waves/SIMD, 2 blk/CU.
// LDS ring: 3 x 16KB (x only) = 48 KB. Per step: [4 wf global loads (k+1)] ->
// [4 ds_read xf(k)] -> [2 gload_lds stage x(k+2)] -> MFMA -> lgkmcnt(0),
// vmcnt(6), s_barrier. vmcnt(6) retires last step's 6 -> x(k+1) landed.
#define KSX 1048576   // shorts: x advance per k-step (4 groups * 32768 * 8)
#define RB  8192      // shorts: ring stride (16KB x)
__global__ __launch_bounds__(512, 4) void conv_mx(
    const u16* __restrict__ wsb, const float* __restrict__ bias,
    float* __restrict__ out) {
    __shared__ __align__(16) u16 lds[3 * RB];     // 49152 B
    const u16* xt = wsb + 524288;
    const u16* wn = wsb + 512;
    const u16* zp = wsb;                          // zero page (memset)

    const int t = threadIdx.x, lane = t & 63, wid = t >> 6;
    const int ll = lane & 15, g = lane >> 4;
    const int mslice = wid >> 1, ncol = wid & 1;

    int wg = ((blockIdx.x & 7) << 7) | (blockIdx.x >> 3);   // XCD swizzle
    const int b = wg >> 7, dt = (wg >> 3) & 15, ht = wg & 7;
    const int d0 = dt * 2, h0 = ht * 4;

    // loop-invariant ds_read offset (shorts, within ring buffer)
    const int pos0 = mslice * 64 + ll;
    const int xro = pos0 * 32 + ((g ^ ((pos0 >> 1) & 3)) * 8);

    // w global-load base: lane (ll,g) reads co=ncol*64+nf*16+ll, ci=g*8
    const u16* wptr = wn + (ncol * 64 + ll) * 32 + g * 8;

    // x staging lane constants (2 gload_lds per thread per k-step)
    const int posA = wid * 32 + (lane >> 2);
    const int slot = lane & 3;
    const int pdA = posA >> 7, phA = (posA >> 5) & 3, wA = posA & 31;
    const int gA = slot ^ ((posA >> 1) & 3);

    f32x4 acc[4][4];
#pragma unroll
    for (int i = 0; i < 4; ++i)
#pragma unroll
        for (int j = 0; j < 4; ++j) acc[i][j] = (f32x4){0.f, 0.f, 0.f, 0.f};

    // staging cursor (2 k-steps ahead of compute)
    int od_s = 0, oh_s = 0, ow_s = 0, cc_s = 0;
    const u16* xsA = xt; bool okA = false, okB = false;

    bf16x8 wa[4], wb[4];   // w fragment double-buffer (regs)

#define WLOAD(WF) { \
    _Pragma("unroll") for (int nf = 0; nf < 4; ++nf) \
        WF[nf] = *(const bf16x8*)&wptr[nf * 512]; \
    wptr += 4096; }

#define DO_STAGE(SB) { \
    if (cc_s == 0) { \
        int Dx = d0 + pdA - 1 + od_s, Hx = h0 + phA - 1 + oh_s, Wx = wA - 1 + ow_s; \
        bool dh_ = ((unsigned)Dx < 32u) && ((unsigned)Hx < 32u); \
        okA = dh_ && ((unsigned)Wx < 32u); \
        okB = dh_ && (Wx < 16); \
        xsA = xt + (long)((b * 16 + gA) * 32768 + Dx * 1024 + Hx * 32 + Wx) * 8; } \
    gload_lds16(okA ? (const void*)xsA : (const void*)zp, (void*)&lds[(SB)*RB + wid*1024]); \
    gload_lds16(okB ? (const void*)(xsA + 128) : (const void*)zp, (void*)&lds[(SB)*RB + wid*1024 + 512]); \
    xsA += KSX; \
    if (++cc_s == 4) { cc_s = 0; \
        if (++ow_s == 3) { ow_s = 0; if (++oh_s == 3) { oh_s = 0; ++od_s; } } } }

#define KSTEP(RD, SB, CW, NW, DOST, DOW, VMSTR) { \
    if (DOW) { WLOAD(NW); } \
    bf16x8 xf0 = *(const bf16x8*)&lds[(RD)*RB + xro]; \
    bf16x8 xf1 = *(const bf16x8*)&lds[(RD)*RB + xro + 512]; \
    if (DOST) { DO_STAGE(SB); } \
    __builtin_amdgcn_s_setprio(1); \
    _Pragma("unroll") for (int nf = 0; nf < 4; ++nf) \
        acc[0][nf] = __builtin_amdgcn_mfma_f32_16x16x32_bf16(CW[nf], xf0, acc[0][nf], 0, 0, 0); \
    _Pragma("unroll") for (int nf = 0; nf < 4; ++nf) \
        acc[1][nf] = __builtin_amdgcn_mfma_f32_16x16x32_bf16(CW[nf], xf1, acc[1][nf], 0, 0, 0); \
    __builtin_amdgcn_s_setprio(0); \
    bf16x8 xf2 = *(const bf16x8*)&lds[(RD)*RB + xro + 1024]; \
    bf16x8 xf3 = *(const bf16x8*)&lds[(RD)*RB + xro + 1536]; \
    __builtin_amdgcn_s_setprio(1); \
    _Pragma("unroll") for (int nf = 0; nf < 4; ++nf) \
        acc[2][nf] = __builtin_amdgcn_mfma_f32_16x16x32_bf16(CW[nf], xf2, acc[2][nf], 0, 0, 0); \
    _Pragma("unroll") for (int nf = 0; nf < 4; ++nf) \
        acc[3][nf] = __builtin_amdgcn_mfma_f32_16x16x32_bf16(CW[nf], xf3, acc[3][nf], 0, 0, 0); \
    __builtin_amdgcn_s_setprio(0); \
    asm volatile("s_waitcnt lgkmcnt(0)" ::: "memory"); \
    asm volatile("s_waitcnt " VMSTR ::: "memory"); \
    asm volatile("s_barrier" ::: "memory"); }

    // prologue: stage x(0)->buf0, x(1)->buf1; load wf(0) into wa
    DO_STAGE(0); DO_STAGE(1);
    WLOAD(wa);
    asm volatile("s_waitcnt vmcnt(6)" ::: "memory");  // x(0) landed (FIFO: x1:2, w0:4)
    asm volatile("s_barrier" ::: "memory");

    for (int m = 0; m < 17; ++m) {      // k = 0..101
        KSTEP(0, 2, wa, wb, 1, 1, "vmcnt(6)");
        KSTEP(1, 0, wb, wa, 1, 1, "vmcnt(6)");
        KSTEP(2, 1, wa, wb, 1, 1, "vmcnt(6)");
        KSTEP(0, 2, wb, wa, 1, 1, "vmcnt(6)");
        KSTEP(1, 0, wa, wb, 1, 1, "vmcnt(6)");
        KSTEP(2, 1, wb, wa, 1, 1, "vmcnt(6)");
    }
    KSTEP(0, 2, wa, wb, 1, 1, "vmcnt(6)");   // k=102, st(104)
    KSTEP(1, 0, wb, wa, 1, 1, "vmcnt(6)");   // k=103, st(105)
    KSTEP(2, 1, wa, wb, 1, 1, "vmcnt(6)");   // k=104, st(106)
    KSTEP(0, 2, wb, wa, 1, 1, "vmcnt(6)");   // k=105, st(107)
    KSTEP(1, 0, wa, wb, 0, 1, "vmcnt(4)");   // k=106, wf(107); drain x(107)
    {   // k=107
        bf16x8 xf0 = *(const bf16x8*)&lds[2 * RB + xro];
        bf16x8 xf1 = *(const bf16x8*)&lds[2 * RB + xro + 512];
        bf16x8 xf2 = *(const bf16x8*)&lds[2 * RB + xro + 1024];
        bf16x8 xf3 = *(const bf16x8*)&lds[2 * RB + xro + 1536];
#pragma unroll
        for (int nf = 0; nf < 4; ++nf) {
            acc[0][nf] = __builtin_amdgcn_mfma_f32_16x16x32_bf16(wb[nf], xf0, acc[0][nf], 0, 0, 0);
            acc[1][nf] = __builtin_amdgcn_mfma_f32_16x16x32_bf16(wb[nf], xf1, acc[1][nf], 0, 0, 0);
            acc[2][nf] = __builtin_amdgcn_mfma_f32_16x16x32_bf16(wb[nf], xf2, acc[2][nf], 0, 0, 0);
            acc[3][nf] = __builtin_amdgcn_mfma_f32_16x16x32_bf16(wb[nf], xf3, acc[3][nf], 0, 0, 0);
        }
    }

    // epilogue: bias + leaky_relu + sqrt(2) + clamp, direct stores
    const int pd = mslice >> 1, phb = (mslice & 1) * 2;
#pragma unroll
    for (int nf = 0; nf < 4; ++nf) {
        f32x4 bb = *(const f32x4*)&bias[ncol * 64 + nf * 16 + g * 4];
#pragma unroll
        for (int mf = 0; mf < 4; ++mf) {
            const int wq = (mf & 1) * 16 + ll;
            const int hh = h0 + phb + (mf >> 1);
            float* orow = out + ((size_t)(b * 128 + ncol * 64 + nf * 16 + g * 4) << 15)
                          + (d0 + pd) * 1024 + hh * 32 + wq;
#pragma unroll
            for (int q = 0; q < 4; ++q) {
                float v = acc[mf][nf][q] + bb[q];
                v = v > 0.f ? v : v * 0.2f;
                v *= 1.41421356237f;
                v = fminf(fmaxf(v, -256.f), 256.f);
                orow[(size_t)q << 15] = v;
            }
        }
    }
#undef WLOAD
#undef DO_STAGE
#undef KSTEP
}

// ---------------- Fallback conv (R4, proven) if ws too small -----------------
#define NPOS 544
__global__ __launch_bounds__(256, 4) void conv_fb(
    const float* __restrict__ x, const u16* __restrict__ wn,
    const float* __restrict__ bias, float* __restrict__ out) {
    __shared__ __align__(16) u16 lds[NPOS * 32];
    float* ldsf = reinterpret_cast<float*>(lds);
    const int t = threadIdx.x;
    const int lane = t & 63;
    const int wid  = t >> 6;
    const int wr   = wid >> 1;
    const int wcn  = wid & 1;
    const int ll   = lane & 15;
    const int g    = lane >> 4;
    const int bid = blockIdx.x;
    const int b  = bid >> 8;
    const int dt = (bid >> 4) & 15, ht = bid & 15;
    const int d0 = dt * 2, h0 = ht * 2;
    const int sw  = t & 31;
    const int sg  = (t >> 5) & 3;
    const int rhi = t >> 7;
    f32x4 acc[4][4];
#pragma unroll
    for (int i = 0; i < 4; ++i)
#pragma unroll
        for (int j = 0; j < 4; ++j) acc[i][j] = (f32x4){0.f, 0.f, 0.f, 0.f};
    float bv[4][4];
#pragma unroll
    for (int nf = 0; nf < 4; ++nf) {
        f32x4 bb = *(const f32x4*)&bias[wcn * 64 + nf * 16 + g * 4];
#pragma unroll
        for (int q = 0; q < 4; ++q) bv[nf][q] = bb[q];
    }
    if (t < 128) {
        int pi  = t >> 2;
        int row = pi >> 1;
        int pos = row * 34 + (pi & 1) * 33;
        bf16x8 z = {0, 0, 0, 0, 0, 0, 0, 0};
        *(bf16x8*)&lds[pos * 32 + (t & 3) * 8] = z;
    }
    for (int c = 0; c < 4; ++c) {
        if (c) __syncthreads();
#pragma unroll
        for (int p = 0; p < 8; ++p) {
            int rowid = p * 2 + rhi;
            int pd = rowid >> 2, ph = rowid & 3;
            int d = d0 - 1 + pd, h = h0 - 1 + ph;
            bool ok = ((unsigned)d < 32u) && ((unsigned)h < 32u);
            const float* src = x + (((b * 128 + c * 32 + sg * 8) * 32 + d) * 32 + h) * 32 + sw;
            float v[8];
#pragma unroll
            for (int j = 0; j < 8; ++j) v[j] = ok ? src[j * 32768] : 0.f;
            bf16x8 pk;
#pragma unroll
            for (int j = 0; j < 8; ++j) pk[j] = (short)f2bf(v[j]);
            int pos = rowid * 34 + sw + 1;
            int sl = sg ^ ((pos >> 1) & 3);
            *(bf16x8*)&lds[pos * 32 + sl * 8] = pk;
        }
        __syncthreads();
        const u16* wbase = wn + c * 4096 + ((wcn * 64 + ll) * 32 + g * 8);
        bf16x8 wf[4];
#pragma unroll
        for (int nf = 0; nf < 4; ++nf) wf[nf] = *(const bf16x8*)&wbase[nf * 512];
#pragma unroll
        for (int tap = 0; tap < 27; ++tap) {
            const int od = tap / 9, oh = (tap / 3) % 3, ow = tap % 3;
            bf16x8 wfn[4];
            if (tap < 26) {
#pragma unroll
                for (int nf = 0; nf < 4; ++nf)
                    wfn[nf] = *(const bf16x8*)&wbase[(tap + 1) * 16384 + nf * 512];
            }
            bf16x8 xf[4];
#pragma unroll
            for (int mf = 0; mf < 4; ++mf) {
                int pos = ((wr + od) * 4 + (mf >> 1) + oh) * 34 + (mf & 1) * 16 + ll + ow;
                int sl = g ^ ((pos >> 1) & 3);
                xf[mf] = *(const bf16x8*)&lds[pos * 32 + sl * 8];
            }
            __builtin_amdgcn_s_setprio(1);
#pragma unroll
            for (int mf = 0; mf < 4; ++mf)
#pragma unroll
                for (int nf = 0; nf < 4; ++nf)
                    acc[mf][nf] = __builtin_amdgcn_mfma_f32_16x16x32_bf16(
                        wf[nf], xf[mf], acc[mf][nf], 0, 0, 0);
            __builtin_amdgcn_s_setprio(0);
            if (tap < 26) {
#pragma unroll
                for (int nf = 0; nf < 4; ++nf) wf[nf] = wfn[nf];
            }
        }
    }
#pragma unroll
    for (int p = 0; p < 4; ++p) {
        const int dd = p >> 1, hh = p & 1;
        __syncthreads();
        if (wr == dd) {
#pragma unroll
            for (int whalf = 0; whalf < 2; ++whalf) {
                const int mf = hh * 2 + whalf;
#pragma unroll
                for (int nf = 0; nf < 4; ++nf) {
#pragma unroll
                    for (int q = 0; q < 4; ++q) {
                        const int co = wcn * 64 + nf * 16 + g * 4 + q;
                        float v = acc[mf][nf][q] + bv[nf][q];
                        v = v > 0.f ? v : v * 0.2f;
                        v *= 1.41421356237f;
                        v = fminf(fmaxf(v, -256.f), 256.f);
                        ldsf[co * 33 + whalf * 16 + ll] = v;
                    }
                }
            }
        }
        __syncthreads();
#pragma unroll
        for (int it = 0; it < 4; ++it) {
            const int row = it * 32 + (t >> 3);
            const int ls  = t & 7;
            f32x4 v = *(f32x4*)&ldsf[row * 33 + ls * 4];
            *(f32x4*)&out[(size_t)(b * 128 + row) * 32768 +
                          (d0 + dd) * 1024 + (h0 + hh) * 32 + ls * 4] = v;
        }
    }
}

extern "C" void kernel_launch(void* const* d_in, const int* in_sizes, int n_in,
                              void* d_out, int out_size, void* d_ws, size_t ws_size,
                              hipStream_t stream) {
    const float* x    = (const float*)d_in[0];
    const float* w    = (const float*)d_in[1];
    const float* bias = (const float*)d_in[2];
    float* out        = (float*)d_out;
    u16* wsb          = (u16*)d_ws;

    hipMemsetAsync(d_ws, 0, 1024, stream);                 // zero page
    prep_w_k<<<128, 256, 0, stream>>>(w, wsb + 512);       // wn at +1KB

    if (ws_size >= 68157440ull) {
        xpose_k<<<8192, 256, 0, stream>>>(x, wsb + 524288);  // xt at +1MB
        conv_mx<<<1024, 512, 0, stream>>>(wsb, bias, out);
    } else {
        conv_fb<<<2048, 256, 0, stream>>>(x, wsb + 512, bias, out);
    }
}

// Round 11
// 291.657 us; speedup vs baseline: 5.4116x; 2.3865x over previous
//
#include <hip/hip_runtime.h>

typedef short bf16x8 __attribute__((ext_vector_type(8)));
typedef float f32x4  __attribute__((ext_vector_type(4)));
typedef unsigned short u16;

static __device__ __forceinline__ u16 f2bf(float f) {
    unsigned int u = __builtin_bit_cast(unsigned int, f);
    u += 0x7FFFu + ((u >> 16) & 1u);   // round-to-nearest-even
    return (u16)(u >> 16);
}

static __device__ __forceinline__ void gload_lds16(const void* g, void* l) {
    __builtin_amdgcn_global_load_lds((const __attribute__((address_space(1))) void*)g,
                                     (__attribute__((address_space(3))) void*)l, 16, 0, 0);
}

// ---------------- Kernel 1: demodulate + convert weights to bf16 -------------
// wn[((tap*4 + cc)*128 + co)*32 + ci_in_chunk]  == kstep-major [k108][co128][ci32]
__global__ __launch_bounds__(256) void prep_w_k(const float* __restrict__ w,
                                                u16* __restrict__ wn) {
    const int co = blockIdx.x;
    const int t  = threadIdx.x;
    const float* wc = w + co * 3456;
    float s = 0.f;
    for (int i = t; i < 3456; i += 256) { float v = wc[i]; s += v * v; }
#pragma unroll
    for (int off = 32; off; off >>= 1) s += __shfl_down(s, off);
    __shared__ float red[4];
    __shared__ float dsh;
    if ((t & 63) == 0) red[t >> 6] = s;
    __syncthreads();
    if (t == 0) dsh = rsqrtf(red[0] + red[1] + red[2] + red[3] + 1e-8f);
    __syncthreads();
    const float d = dsh;
    for (int i = t; i < 3456; i += 256) {
        int ci = i / 27, tap = i - ci * 27;
        float v = wc[i] * d;
        wn[((tap * 4 + (ci >> 5)) * 128 + co) * 32 + (ci & 31)] = f2bf(v);
    }
}

// ---------------- Kernel 2: transpose x -> channels-grouped bf16 -------------
// xt[((b*16 + g)*32768 + d*1024 + h*32 + w)*8 + j] = bf16(x[b][g*8+j][d][h][w])
__global__ __launch_bounds__(256) void xpose_k(const float* __restrict__ x,
                                               u16* __restrict__ xt) {
    const int bid = blockIdx.x;
    const int b = bid >> 10, d = (bid >> 5) & 31, h = bid & 31;
    const int t = threadIdx.x;
    const int w = t & 31, cg = t >> 5;
    const int base_dhw = d * 1024 + h * 32 + w;
#pragma unroll
    for (int r = 0; r < 2; ++r) {
        int g = cg + r * 8;
        const float* src = x + ((size_t)(b * 128 + g * 8) << 15) + base_dhw;
        bf16x8 pk;
#pragma unroll
        for (int j = 0; j < 8; ++j) pk[j] = (short)f2bf(src[(size_t)j << 15]);
        *(bf16x8*)&xt[((size_t)((b * 16 + g) << 15) + base_dhw) * 8] = pk;
    }
}

// ---------------- Kernel 3: conv3d, reg-dbuf frags + ring-3, ILP regime ------
// 512 thr = 8 waves (4 M-slices x 2 co-halves). Tile M=256 (d2,h4,w32), N=128.
// __launch_bounds__(512,2): 256-VGPR budget, 1 block/CU, 2 waves/SIMD.
// LDS ring: 3 x (x 16KB + w 8KB) = 72 KB. Step k: ds_read frags(k+1) from
// buf (k+1)%3 -> stage st(k+3) into buf k%3 -> MFMA frags(k) (in regs) ->
// lgkmcnt(0), vmcnt(3) [forces st(k+1) landed; st(k+2),st(k+3) in flight],
// s_barrier. CORRECT count: at the wait, FIFO = {st(k+2):3, st(k+3):3}; the
// NEXT step reads frags(k+2)... no: reads frags(k+1)?? -- step k+1 reads
// frags(k+2), which st landed by the wait at end of step k+1's predecessor?
// Invariant proven in R10 analysis: barrier ending step k guarantees st(k+2)
// landed (vmcnt(3) leaves only st(k+3) in flight... exactly: 6 outstanding,
// wait<=3 retires st(k+2)) -> step k+1's RDFRAG(frags(k+2)) is safe.
#define KSX 1048576   // shorts: x advance per k-step (4 groups * 32768 * 8)
#define KSW 4096      // shorts: wn advance per k-step
#define RB  12288     // shorts: ring stride (8192 x + 4096 w)
__global__ __launch_bounds__(512, 2) void conv_mx(
    const u16* __restrict__ wsb, const float* __restrict__ bias,
    float* __restrict__ out) {
    __shared__ __align__(16) u16 lds[3 * RB];     // 73728 B
    const u16* xt = wsb + 524288;
    const u16* wn = wsb + 512;
    const u16* zp = wsb;                          // zero page (memset)

    const int t = threadIdx.x, lane = t & 63, wid = t >> 6;
    const int ll = lane & 15, g = lane >> 4;
    const int mslice = wid >> 1, ncol = wid & 1;

    int wg = ((blockIdx.x & 7) << 7) | (blockIdx.x >> 3);   // XCD swizzle
    const int b = wg >> 7, dt = (wg >> 3) & 15, ht = wg & 7;
    const int d0 = dt * 2, h0 = ht * 4;

    // loop-invariant ds_read offsets (shorts, within ring buffer)
    const int pos0 = mslice * 64 + ll;
    const int xro = pos0 * 32 + ((g ^ ((pos0 >> 1) & 3)) * 8);
    const int co0 = ncol * 64 + ll;
    const int wro = 8192 + co0 * 32 + ((g ^ ((co0 >> 1) & 3)) * 8);

    // staging lane constants (3 gload_lds per thread per k-step)
    const int posA = wid * 32 + (lane >> 2);
    const int slot = lane & 3;
    const int pdA = posA >> 7, phA = (posA >> 5) & 3, wA = posA & 31;
    const int gA = slot ^ ((posA >> 1) & 3);
    const int wco = wid * 16 + (lane >> 2);
    const u16* wsrc = wn + wco * 32 + ((slot ^ ((wco >> 1) & 3)) * 8);

    f32x4 acc[4][4];
#pragma unroll
    for (int i = 0; i < 4; ++i)
#pragma unroll
        for (int j = 0; j < 4; ++j) acc[i][j] = (f32x4){0.f, 0.f, 0.f, 0.f};

    // staging cursor
    int od_s = 0, oh_s = 0, ow_s = 0, cc_s = 0;
    const u16* xsA = xt; bool okA = false, okB = false;

    bf16x8 xa[4], wa[4], xb[4], wb[4];   // frag double-buffer

#define DO_STAGE(SB) { \
    if (cc_s == 0) { \
        int Dx = d0 + pdA - 1 + od_s, Hx = h0 + phA - 1 + oh_s, Wx = wA - 1 + ow_s; \
        bool dh_ = ((unsigned)Dx < 32u) && ((unsigned)Hx < 32u); \
        okA = dh_ && ((unsigned)Wx < 32u); \
        okB = dh_ && (Wx < 16); \
        xsA = xt + (long)((b * 16 + gA) * 32768 + Dx * 1024 + Hx * 32 + Wx) * 8; } \
    gload_lds16(okA ? (const void*)xsA : (const void*)zp, (void*)&lds[(SB)*RB + wid*1024]); \
    gload_lds16(okB ? (const void*)(xsA + 128) : (const void*)zp, (void*)&lds[(SB)*RB + wid*1024 + 512]); \
    gload_lds16((const void*)wsrc, (void*)&lds[(SB)*RB + 8192 + wid*512]); \
    xsA += KSX; wsrc += KSW; \
    if (++cc_s == 4) { cc_s = 0; \
        if (++ow_s == 3) { ow_s = 0; if (++oh_s == 3) { oh_s = 0; ++od_s; } } } }

#define RDFRAG(RD, XF, WF) { \
    _Pragma("unroll") for (int mf = 0; mf < 4; ++mf) \
        XF[mf] = *(const bf16x8*)&lds[(RD)*RB + xro + mf * 512]; \
    _Pragma("unroll") for (int nf = 0; nf < 4; ++nf) \
        WF[nf] = *(const bf16x8*)&lds[(RD)*RB + wro + nf * 512]; }

#define MFMACL(XF, WF) { \
    __builtin_amdgcn_s_setprio(1); \
    _Pragma("unroll") for (int mf = 0; mf < 4; ++mf) \
    _Pragma("unroll") for (int nf = 0; nf < 4; ++nf) \
        acc[mf][nf] = __builtin_amdgcn_mfma_f32_16x16x32_bf16(WF[nf], XF[mf], acc[mf][nf], 0, 0, 0); \
    __builtin_amdgcn_s_setprio(0); }

#define KSTEP(RD, SB, CX, CW, NX, NW, DOST, VMSTR) { \
    RDFRAG(RD, NX, NW); \
    if (DOST) DO_STAGE(SB); \
    MFMACL(CX, CW); \
    asm volatile("s_waitcnt lgkmcnt(0)" ::: "memory"); \
    asm volatile("s_waitcnt " VMSTR ::: "memory"); \
    asm volatile("s_barrier" ::: "memory"); }

    // prologue: stage k=0,1,2 into buf0,1,2
    DO_STAGE(0); DO_STAGE(1); DO_STAGE(2);          // 9 loads in flight
    asm volatile("s_waitcnt vmcnt(6)" ::: "memory"); // st(0) landed (mine)
    asm volatile("s_barrier" ::: "memory");          // st(0) landed (all)
    RDFRAG(0, xa, wa);                               // frags(0) -> A
    asm volatile("s_waitcnt lgkmcnt(0)" ::: "memory");
    asm volatile("s_waitcnt vmcnt(3)" ::: "memory"); // st(1) landed (mine)
    asm volatile("s_barrier" ::: "memory");          // frags(0) captured + st(1) all

    for (int m = 0; m < 17; ++m) {      // k = 0..101
        KSTEP(1, 0, xa, wa, xb, wb, 1, "vmcnt(3)");
        KSTEP(2, 1, xb, wb, xa, wa, 1, "vmcnt(3)");
        KSTEP(0, 2, xa, wa, xb, wb, 1, "vmcnt(3)");
        KSTEP(1, 0, xb, wb, xa, wa, 1, "vmcnt(3)");
        KSTEP(2, 1, xa, wa, xb, wb, 1, "vmcnt(3)");
        KSTEP(0, 2, xb, wb, xa, wa, 1, "vmcnt(3)");
    }
    KSTEP(1, 0, xa, wa, xb, wb, 1, "vmcnt(3)");     // k=102, st(105)
    KSTEP(2, 1, xb, wb, xa, wa, 1, "vmcnt(3)");     // k=103, st(106)
    KSTEP(0, 2, xa, wa, xb, wb, 1, "vmcnt(3)");     // k=104, st(107)
    KSTEP(1, 0, xb, wb, xa, wa, 0, "vmcnt(0)");     // k=105
    KSTEP(2, 0, xa, wa, xb, wb, 0, "vmcnt(0)");     // k=106
    MFMACL(xb, wb);                                  // k=107

    // epilogue: bias + leaky_relu + sqrt(2) + clamp, direct stores
    const int pd = mslice >> 1, phb = (mslice & 1) * 2;
#pragma unroll
    for (int nf = 0; nf < 4; ++nf) {
        f32x4 bb = *(const f32x4*)&bias[ncol * 64 + nf * 16 + g * 4];
#pragma unroll
        for (int mf = 0; mf < 4; ++mf) {
            const int wq = (mf & 1) * 16 + ll;
            const int hh = h0 + phb + (mf >> 1);
            float* orow = out + ((size_t)(b * 128 + ncol * 64 + nf * 16 + g * 4) << 15)
                          + (d0 + pd) * 1024 + hh * 32 + wq;
#pragma unroll
            for (int q = 0; q < 4; ++q) {
                float v = acc[mf][nf][q] + bb[q];
                v = v > 0.f ? v : v * 0.2f;
                v *= 1.41421356237f;
                v = fminf(fmaxf(v, -256.f), 256.f);
                orow[(size_t)q << 15] = v;
            }
        }
    }
#undef DO_STAGE
#undef RDFRAG
#undef MFMACL
#undef KSTEP
}

// ---------------- Fallback conv (R4, proven) if ws too small -----------------
#define NPOS 544
__global__ __launch_bounds__(256, 4) void conv_fb(
    const float* __restrict__ x, const u16* __restrict__ wn,
    const float* __restrict__ bias, float* __restrict__ out) {
    __shared__ __align__(16) u16 lds[NPOS * 32];
    float* ldsf = reinterpret_cast<float*>(lds);
    const int t = threadIdx.x;
    const int lane = t & 63;
    const int wid  = t >> 6;
    const int wr   = wid >> 1;
    const int wcn  = wid & 1;
    const int ll   = lane & 15;
    const int g    = lane >> 4;
    const int bid = blockIdx.x;
    const int b  = bid >> 8;
    const int dt = (bid >> 4) & 15, ht = bid & 15;
    const int d0 = dt * 2, h0 = ht * 2;
    const int sw  = t & 31;
    const int sg  = (t >> 5) & 3;
    const int rhi = t >> 7;
    f32x4 acc[4][4];
#pragma unroll
    for (int i = 0; i < 4; ++i)
#pragma unroll
        for (int j = 0; j < 4; ++j) acc[i][j] = (f32x4){0.f, 0.f, 0.f, 0.f};
    float bv[4][4];
#pragma unroll
    for (int nf = 0; nf < 4; ++nf) {
        f32x4 bb = *(const f32x4*)&bias[wcn * 64 + nf * 16 + g * 4];
#pragma unroll
        for (int q = 0; q < 4; ++q) bv[nf][q] = bb[q];
    }
    if (t < 128) {
        int pi  = t >> 2;
        int row = pi >> 1;
        int pos = row * 34 + (pi & 1) * 33;
        bf16x8 z = {0, 0, 0, 0, 0, 0, 0, 0};
        *(bf16x8*)&lds[pos * 32 + (t & 3) * 8] = z;
    }
    for (int c = 0; c < 4; ++c) {
        if (c) __syncthreads();
#pragma unroll
        for (int p = 0; p < 8; ++p) {
            int rowid = p * 2 + rhi;
            int pd = rowid >> 2, ph = rowid & 3;
            int d = d0 - 1 + pd, h = h0 - 1 + ph;
            bool ok = ((unsigned)d < 32u) && ((unsigned)h < 32u);
            const float* src = x + (((b * 128 + c * 32 + sg * 8) * 32 + d) * 32 + h) * 32 + sw;
            float v[8];
#pragma unroll
            for (int j = 0; j < 8; ++j) v[j] = ok ? src[j * 32768] : 0.f;
            bf16x8 pk;
#pragma unroll
            for (int j = 0; j < 8; ++j) pk[j] = (short)f2bf(v[j]);
            int pos = rowid * 34 + sw + 1;
            int sl = sg ^ ((pos >> 1) & 3);
            *(bf16x8*)&lds[pos * 32 + sl * 8] = pk;
        }
        __syncthreads();
        const u16* wbase = wn + c * 4096 + ((wcn * 64 + ll) * 32 + g * 8);
        bf16x8 wf[4];
#pragma unroll
        for (int nf = 0; nf < 4; ++nf) wf[nf] = *(const bf16x8*)&wbase[nf * 512];
#pragma unroll
        for (int tap = 0; tap < 27; ++tap) {
            const int od = tap / 9, oh = (tap / 3) % 3, ow = tap % 3;
            bf16x8 wfn[4];
            if (tap < 26) {
#pragma unroll
                for (int nf = 0; nf < 4; ++nf)
                    wfn[nf] = *(const bf16x8*)&wbase[(tap + 1) * 16384 + nf * 512];
            }
            bf16x8 xf[4];
#pragma unroll
            for (int mf = 0; mf < 4; ++mf) {
                int pos = ((wr + od) * 4 + (mf >> 1) + oh) * 34 + (mf & 1) * 16 + ll + ow;
                int sl = g ^ ((pos >> 1) & 3);
                xf[mf] = *(const bf16x8*)&lds[pos * 32 + sl * 8];
            }
            __builtin_amdgcn_s_setprio(1);
#pragma unroll
            for (int mf = 0; mf < 4; ++mf)
#pragma unroll
                for (int nf = 0; nf < 4; ++nf)
                    acc[mf][nf] = __builtin_amdgcn_mfma_f32_16x16x32_bf16(
                        wf[nf], xf[mf], acc[mf][nf], 0, 0, 0);
            __builtin_amdgcn_s_setprio(0);
            if (tap < 26) {
#pragma unroll
                for (int nf = 0; nf < 4; ++nf) wf[nf] = wfn[nf];
            }
        }
    }
#pragma unroll
    for (int p = 0; p < 4; ++p) {
        const int dd = p >> 1, hh = p & 1;
        __syncthreads();
        if (wr == dd) {
#pragma unroll
            for (int whalf = 0; whalf < 2; ++whalf) {
                const int mf = hh * 2 + whalf;
#pragma unroll
                for (int nf = 0; nf < 4; ++nf) {
#pragma unroll
                    for (int q = 0; q < 4; ++q) {
                        const int co = wcn * 64 + nf * 16 + g * 4 + q;
                        float v = acc[mf][nf][q] + bv[nf][q];
                        v = v > 0.f ? v : v * 0.2f;
                        v *= 1.41421356237f;
                        v = fminf(fmaxf(v, -256.f), 256.f);
                        ldsf[co * 33 + whalf * 16 + ll] = v;
                    }
                }
            }
        }
        __syncthreads();
#pragma unroll
        for (int it = 0; it < 4; ++it) {
            const int row = it * 32 + (t >> 3);
            const int ls  = t & 7;
            f32x4 v = *(f32x4*)&ldsf[row * 33 + ls * 4];
            *(f32x4*)&out[(size_t)(b * 128 + row) * 32768 +
                          (d0 + dd) * 1024 + (h0 + hh) * 32 + ls * 4] = v;
        }
    }
}

extern "C" void kernel_launch(void* const* d_in, const int* in_sizes, int n_in,
                              void* d_out, int out_size, void* d_ws, size_t ws_size,
                              hipStream_t stream) {
    const float* x    = (const float*)d_in[0];
    const float* w    = (const float*)d_in[1];
    const float* bias = (const float*)d_in[2];
    float* out        = (float*)d_out;
    u16* wsb          = (u16*)d_ws;

    hipMemsetAsync(d_ws, 0, 1024, stream);                 // zero page
    prep_w_k<<<128, 256, 0, stream>>>(w, wsb + 512);       // wn at +1KB

    if (ws_size >= 68157440ull) {
        xpose_k<<<8192, 256, 0, stream>>>(x, wsb + 524288);  // xt at +1MB
        conv_mx<<<1024, 512, 0, stream>>>(wsb, bias, out);
    } else {
        conv_fb<<<2048, 256, 0, stream>>>(x, wsb + 512, bias, out);
    }
}